// Round 13
// baseline (3841.176 us; speedup 1.0000x reference)
//
#include <hip/hip_runtime.h>
#include <hip/hip_bf16.h>
#include <float.h>
#include <math.h>

#define BN   4096
#define DD   112
#define HH   512
#define G3   1536
#define CW   536
#define CWP  544     // K padded to 17*32
#define HIDD 512

typedef __attribute__((ext_vector_type(8))) short short8;
typedef __attribute__((ext_vector_type(4))) float float4v;
typedef __attribute__((ext_vector_type(2))) long long2v;

__device__ __forceinline__ unsigned short f2bf(float x) {
    __hip_bfloat16 h = __float2bfloat16(x);
    return *(unsigned short*)&h;
}
// HW-native OCP e4m3 conversion (gfx950)
__device__ __forceinline__ unsigned char f2fp8(float x) {
    int v = __builtin_amdgcn_cvt_pk_fp8_f32(x, x, 0, false);
    return (unsigned char)(v & 0xff);
}

// ---------------- const = [c | b | m | 0pad]  (B x 544) bf16 ----------------
__global__ void build_constbf(const float* __restrict__ c, const float* __restrict__ b,
                              const float* __restrict__ m, unsigned short* __restrict__ out) {
    int idx = blockIdx.x * blockDim.x + threadIdx.x;
    if (idx >= BN * CWP) return;
    int row = idx / CWP, col = idx - row * CWP;
    float v;
    if (col < 312)      v = c[row * 312 + col];
    else if (col < 424) v = b[row * 112 + (col - 312)];
    else if (col < 536) v = m[row * 112 + (col - 424)];
    else                v = 0.0f;
    out[idx] = f2bf(v);
}

__global__ void zero_f32(float* __restrict__ p, int n) {
    int i = blockIdx.x * blockDim.x + threadIdx.x;
    if (i < n) p[i] = 0.0f;
}

// ---------------- pack weight [K][N] -> bf16 MFMA B-fragments (zero-padded) ----------------
__global__ void pack_wN(const float* __restrict__ src, unsigned short* __restrict__ dst,
                        int kchunks, int ldn, int ncols, int nrows) {
    int bid = blockIdx.x;
    int nt = bid / kchunks, kc = bid - nt * kchunks;
    int lane = threadIdx.x;
    int quad = lane >> 4, l16 = lane & 15;
    int n = nt * 16 + l16;
    unsigned short v[8];
#pragma unroll
    for (int j = 0; j < 8; ++j) {
        int k = kc * 32 + quad * 8 + j;
        float f = (k < nrows && n < ncols) ? src[(size_t)k * ldn + n] : 0.0f;
        v[j] = f2bf(f);
    }
    unsigned short* p = dst + ((size_t)bid * 64 + lane) * 8;
#pragma unroll
    for (int j = 0; j < 8; ++j) p[j] = v[j];
}

// ---------------- pack weight [K][N] -> PAIRED fp8 e4m3 fragments ----------------
// One 16B store = fragments (kc=2*kp) and (kc=2*kp+1): bytes 0..7 even kc, 8..15 odd kc.
__global__ void pack_w8p(const float* __restrict__ src, unsigned char* __restrict__ dst,
                         int ldn) {
    int bid = blockIdx.x;                 // nt*8 + kp, nt < 96
    int nt = bid >> 3, kp = bid & 7;
    int lane = threadIdx.x;
    int quad = lane >> 4, l16 = lane & 15;
    int n = nt * 16 + l16;
    unsigned char v[16];
#pragma unroll
    for (int j2 = 0; j2 < 16; ++j2) {
        int k = kp * 64 + (j2 >> 3) * 32 + quad * 8 + (j2 & 7);
        v[j2] = f2fp8(src[(size_t)k * ldn + n]);
    }
    unsigned char* p = dst + ((size_t)bid * 64 + lane) * 16;
#pragma unroll
    for (int j2 = 0; j2 < 16; ++j2) p[j2] = v[j2];
}

// ---------------- bf16 MFMA GEMM: C[B x N] = A[B x 544] @ Wp + bias ----------------
template<int TPW>
__global__ __launch_bounds__(1024) void gemm_const_mfma(
    const unsigned short* __restrict__ A, const unsigned short* __restrict__ BP,
    const float* __restrict__ bias, float* __restrict__ C, int N)
{
    const int tid = threadIdx.x;
    const int wave = tid >> 6, lane = tid & 63;
    const int quad = lane >> 4, l16 = lane & 15;
    const int rowBase = blockIdx.x * 16;
    const short8* BF = (const short8*)BP;
    float4v acc[TPW];
#pragma unroll
    for (int i = 0; i < TPW; ++i) {
        float bv = bias[(wave + 16 * i) * 16 + l16];
        acc[i] = (float4v){bv, bv, bv, bv};
    }
#pragma unroll 4
    for (int kc = 0; kc < 17; ++kc) {
        short8 af = *(const short8*)&A[(size_t)(rowBase + l16) * CWP + kc * 32 + quad * 8];
#pragma unroll
        for (int i = 0; i < TPW; ++i) {
            int tile = wave + 16 * i;
            acc[i] = __builtin_amdgcn_mfma_f32_16x16x32_bf16(af, BF[(tile * 17 + kc) * 64 + lane], acc[i], 0, 0, 0);
        }
    }
#pragma unroll
    for (int i = 0; i < TPW; ++i) {
        int col = (wave + 16 * i) * 16 + l16;
#pragma unroll
        for (int rg = 0; rg < 4; ++rg)
            C[(size_t)(rowBase + quad * 4 + rg) * N + col] = acc[i][rg];
    }
}

// ---------------- mask = descending sort of m*(1-b) per row ----------------
__global__ void sort_mask(const float* __restrict__ b, const float* __restrict__ m,
                          float* __restrict__ maskbuf) {
    __shared__ float s[128];
    const int row = blockIdx.x, t = threadIdx.x;
    float v = -FLT_MAX;
    if (t < DD) v = m[row * DD + t] * (1.0f - b[row * DD + t]);
    s[t] = v;
    __syncthreads();
    for (int k = 2; k <= 128; k <<= 1) {
        for (int j = k >> 1; j > 0; j >>= 1) {
            int ixj = t ^ j;
            if (ixj > t) {
                bool up = ((t & k) == 0);
                float a = s[t], bb = s[ixj];
                if ((a > bb) == up) { s[t] = bb; s[ixj] = a; }
            }
            __syncthreads();
        }
    }
    if (t < DD) maskbuf[row * DD + t] = s[127 - t];
}

// ================= KERNEL A: GRU recurrence chunk — all-fp8 gates, PAIRED loads =================
// 48 weight-load instructions/wave/step (was 96). h master fp32 in regs; bf16 mirror
// only feeds the h2g slab (head numerics unchanged); fp8 mirror feeds gate MFMAs.
__global__ __launch_bounds__(1024, 4) void gru_rec_chunk(
    const float* __restrict__ z, const float* __restrict__ Wih,
    const float* __restrict__ bhh, const float* __restrict__ gi_const,
    const unsigned char* __restrict__ Whh8P,
    float* __restrict__ hstate, unsigned short* __restrict__ h2g,
    int t0, int tlen)
{
    __shared__ unsigned short h_bf[2][16 * 520];
    __shared__ unsigned char h8[2][16 * 528];   // paired layout: kp*64 + quad*16 + odd*8 + j
    __shared__ float zbuf[113 * 16];

    const int tid = threadIdx.x;
    const int wave = tid >> 6, lane = tid & 63;
    const int quad = lane >> 4, l16 = lane & 15;
    const int rowBase = blockIdx.x * 16;

    for (int idx = tid; idx < 113 * 16; idx += 1024) {
        int tt = idx >> 4, r = idx & 15;
        zbuf[idx] = (tt == 0) ? -1.0f : z[(rowBase + r) * DD + tt - 1];
    }

    int hcol[2], h8off[2];
    float wz0[2], wz1[2], wz2[2], bh2r[2];
    float gic0[2][4], gic1[2][4], gic2[2][4];
    float h_own[2][4];
#pragma unroll
    for (int i = 0; i < 2; ++i) {
        int tile = wave + 16 * i;
        int hc = tile * 16 + l16;
        hcol[i] = hc;
        {   // paired-fp8 layout offset for column hc
            int kp = hc >> 6, rem = hc & 63;
            h8off[i] = kp * 64 + ((rem & 31) >> 3) * 16 + (rem >> 5) * 8 + (rem & 7);
        }
        wz0[i] = Wih[hc]; wz1[i] = Wih[512 + hc]; wz2[i] = Wih[1024 + hc];
        float bh0 = bhh[hc], bh1 = bhh[512 + hc];
        bh2r[i] = bhh[1024 + hc];
#pragma unroll
        for (int rg = 0; rg < 4; ++rg) {
            int m = quad * 4 + rg;
            const float* g = gi_const + (size_t)(rowBase + m) * G3;
            gic0[i][rg] = g[hc] + bh0;
            gic1[i][rg] = g[512 + hc] + bh1;
            gic2[i][rg] = g[1024 + hc];
            float hv = hstate[(size_t)(rowBase + m) * HH + hc];
            h_own[i][rg] = hv;
            h_bf[0][m * 520 + hc] = f2bf(hv);
            h8[0][m * 528 + h8off[i]] = f2fp8(hv);
        }
    }
    const long2v* W8F = (const long2v*)Whh8P;
    __syncthreads();

    for (int tt = 0; tt < tlen; ++tt) {
        const int t = t0 + tt;
        const int p = tt & 1;
        const unsigned char* h8src = h8[p];
        unsigned short* hdst = h_bf[p ^ 1];
        unsigned char* h8dst = h8[p ^ 1];
        float4v accR[2], accU[2], accN[2];
#pragma unroll
        for (int i = 0; i < 2; ++i) {
            accR[i] = (float4v){gic0[i][0], gic0[i][1], gic0[i][2], gic0[i][3]};
            accU[i] = (float4v){gic1[i][0], gic1[i][1], gic1[i][2], gic1[i][3]};
            accN[i] = (float4v){0.f, 0.f, 0.f, 0.f};
        }
#pragma unroll 8
        for (int kp = 0; kp < 8; ++kp) {
            long2v afp = *(const long2v*)&h8src[l16 * 528 + kp * 64 + quad * 16];
#pragma unroll
            for (int i = 0; i < 2; ++i) {
                int tile = wave + 16 * i;
                long2v wR = W8F[((tile) * 8 + kp) * 64 + lane];
                long2v wU = W8F[((tile + 32) * 8 + kp) * 64 + lane];
                long2v wN = W8F[((tile + 64) * 8 + kp) * 64 + lane];
                accR[i] = __builtin_amdgcn_mfma_f32_16x16x32_fp8_fp8(afp.x, wR.x, accR[i], 0, 0, 0);
                accR[i] = __builtin_amdgcn_mfma_f32_16x16x32_fp8_fp8(afp.y, wR.y, accR[i], 0, 0, 0);
                accU[i] = __builtin_amdgcn_mfma_f32_16x16x32_fp8_fp8(afp.x, wU.x, accU[i], 0, 0, 0);
                accU[i] = __builtin_amdgcn_mfma_f32_16x16x32_fp8_fp8(afp.y, wU.y, accU[i], 0, 0, 0);
                accN[i] = __builtin_amdgcn_mfma_f32_16x16x32_fp8_fp8(afp.x, wN.x, accN[i], 0, 0, 0);
                accN[i] = __builtin_amdgcn_mfma_f32_16x16x32_fp8_fp8(afp.y, wN.y, accN[i], 0, 0, 0);
            }
        }
        // nonlin: reads regs, writes OTHER buffers -> no barrier before writes
#pragma unroll
        for (int i = 0; i < 2; ++i) {
#pragma unroll
            for (int rg = 0; rg < 4; ++rg) {
                int m = quad * 4 + rg;
                float zt = zbuf[t * 16 + m];
                float r = 1.0f / (1.0f + __expf(-(accR[i][rg] + zt * wz0[i])));
                float u = 1.0f / (1.0f + __expf(-(accU[i][rg] + zt * wz1[i])));
                float xn = gic2[i][rg] + zt * wz2[i] + r * (accN[i][rg] + bh2r[i]);
                float n = 1.0f - 2.0f / (__expf(2.0f * xn) + 1.0f);
                float h2 = (1.0f - u) * n + u * h_own[i][rg];
                h_own[i][rg] = h2;
                hdst[m * 520 + hcol[i]] = f2bf(h2);
                h8dst[m * 528 + h8off[i]] = f2fp8(h2);
            }
        }
        __syncthreads();  // single barrier: hdst/h8dst complete
        {
            int col = lane * 8;
            uint4 v = *(const uint4*)&hdst[wave * 520 + col];
            *(uint4*)&h2g[((size_t)tt * BN + rowBase + wave) * 512 + col] = v;
        }
    }
#pragma unroll
    for (int i = 0; i < 2; ++i)
#pragma unroll
        for (int rg = 0; rg < 4; ++rg)
            hstate[(size_t)(rowBase + quad * 4 + rg) * HH + hcol[i]] = h_own[i][rg];
}

// ================= KERNEL B: MLP head + MDN, M=64 (R10/R12-proven, unchanged) =================
__global__ __launch_bounds__(1024) void head_mdn64(
    const float* __restrict__ z, const float* __restrict__ b1,
    const float* __restrict__ b2, const float* __restrict__ mlp_const,
    const float* __restrict__ maskbuf, const unsigned short* __restrict__ h2g,
    const unsigned short* __restrict__ W0hP, const unsigned short* __restrict__ W1P,
    const unsigned short* __restrict__ W2P, float* __restrict__ out, int t0)
{
    __shared__ unsigned short h_bf[64 * 520];   // h2, later a2
    __shared__ unsigned short a_bf[64 * 520];   // a1, later pp (float alias)
    float* ppf = (float*)a_bf;

    const int tid = threadIdx.x;
    const int wave = tid >> 6, lane = tid & 63;
    const int quad = lane >> 4, l16 = lane & 15;
    const int pr = tid >> 5, pc = tid & 31;
    const int b0 = blockIdx.x * 4;
    const int tg = blockIdx.y;
    const int phase = blockIdx.x & 15;

    {
        int flat = tid * 32;
        int r = flat >> 9, col = flat & 511;
        int bb = b0 + (r >> 4), trel = tg * 16 + (r & 15);
        const uint4* src = (const uint4*)&h2g[((size_t)trel * BN + bb) * 512 + col];
        uint4 v0 = src[0], v1 = src[1], v2 = src[2], v3 = src[3];
        uint4* dst = (uint4*)&h_bf[r * 520 + col];
        dst[0] = v0; dst[1] = v1; dst[2] = v2; dst[3] = v3;
    }
    int hcol[2];
    float b1c[2], mlc[2][4];
#pragma unroll
    for (int i = 0; i < 2; ++i) {
        int hc = (wave + 16 * i) * 16 + l16;
        hcol[i] = hc;
        b1c[i] = b1[hc];
#pragma unroll
        for (int mt = 0; mt < 4; ++mt) mlc[i][mt] = mlp_const[(size_t)(b0 + mt) * HIDD + hc];
    }
    const float b2v = (pc < 30) ? b2[pc] : 0.0f;
    const short8* W0hF = (const short8*)W0hP;
    const short8* W1F  = (const short8*)W1P;
    const short8* W2F  = (const short8*)W2P;
    __syncthreads();  // S0: h staged

    float4v acc1[2][4];
#pragma unroll
    for (int i = 0; i < 2; ++i)
#pragma unroll
        for (int mt = 0; mt < 4; ++mt)
            acc1[i][mt] = (float4v){mlc[i][mt], mlc[i][mt], mlc[i][mt], mlc[i][mt]};
#pragma unroll 2
    for (int kk = 0; kk < 16; ++kk) {
        const int kc = (kk + phase) & 15;
        short8 af[4];
#pragma unroll
        for (int mt = 0; mt < 4; ++mt)
            af[mt] = *(const short8*)&h_bf[(mt * 16 + l16) * 520 + kc * 32 + quad * 8];
#pragma unroll
        for (int i = 0; i < 2; ++i) {
            short8 bf = W0hF[((wave + 16 * i) * 16 + kc) * 64 + lane];
#pragma unroll
            for (int mt = 0; mt < 4; ++mt)
                acc1[i][mt] = __builtin_amdgcn_mfma_f32_16x16x32_bf16(af[mt], bf, acc1[i][mt], 0, 0, 0);
        }
    }
#pragma unroll
    for (int i = 0; i < 2; ++i)
#pragma unroll
        for (int mt = 0; mt < 4; ++mt)
#pragma unroll
            for (int rg = 0; rg < 4; ++rg) {
                int m = mt * 16 + quad * 4 + rg;
                float x = acc1[i][mt][rg];
                a_bf[m * 520 + hcol[i]] = f2bf(1.0f - 2.0f / (__expf(2.0f * x) + 1.0f));
            }
    __syncthreads();  // S1: a1 ready
    float4v acc2[2][4];
#pragma unroll
    for (int i = 0; i < 2; ++i)
#pragma unroll
        for (int mt = 0; mt < 4; ++mt)
            acc2[i][mt] = (float4v){b1c[i], b1c[i], b1c[i], b1c[i]};
#pragma unroll 2
    for (int kk = 0; kk < 16; ++kk) {
        const int kc = (kk + phase) & 15;
        short8 af[4];
#pragma unroll
        for (int mt = 0; mt < 4; ++mt)
            af[mt] = *(const short8*)&a_bf[(mt * 16 + l16) * 520 + kc * 32 + quad * 8];
#pragma unroll
        for (int i = 0; i < 2; ++i) {
            short8 bf = W1F[((wave + 16 * i) * 16 + kc) * 64 + lane];
#pragma unroll
            for (int mt = 0; mt < 4; ++mt)
                acc2[i][mt] = __builtin_amdgcn_mfma_f32_16x16x32_bf16(af[mt], bf, acc2[i][mt], 0, 0, 0);
        }
    }
    __syncthreads();  // S2: a1 reads done
#pragma unroll
    for (int i = 0; i < 2; ++i)
#pragma unroll
        for (int mt = 0; mt < 4; ++mt)
#pragma unroll
            for (int rg = 0; rg < 4; ++rg) {
                int m = mt * 16 + quad * 4 + rg;
                float x = acc2[i][mt][rg];
                h_bf[m * 520 + hcol[i]] = f2bf(1.0f - 2.0f / (__expf(2.0f * x) + 1.0f));
            }
    __syncthreads();  // S3: a2 ready
    {
        const int mtw = wave >> 2, kg = wave & 3;
        float4v ap0 = (float4v){0.f, 0.f, 0.f, 0.f}, ap1 = (float4v){0.f, 0.f, 0.f, 0.f};
#pragma unroll
        for (int kk = 0; kk < 4; ++kk) {
            int kc = kg * 4 + kk;
            short8 af = *(const short8*)&h_bf[(mtw * 16 + l16) * 520 + kc * 32 + quad * 8];
            ap0 = __builtin_amdgcn_mfma_f32_16x16x32_bf16(af, W2F[(0 * 16 + kc) * 64 + lane], ap0, 0, 0, 0);
            ap1 = __builtin_amdgcn_mfma_f32_16x16x32_bf16(af, W2F[(1 * 16 + kc) * 64 + lane], ap1, 0, 0, 0);
        }
#pragma unroll
        for (int rg = 0; rg < 4; ++rg) {
            ppf[((kg * 4 + mtw) * 2 + 0) * 256 + lane * 4 + rg] = ap0[rg];
            ppf[((kg * 4 + mtw) * 2 + 1) * 256 + lane * 4 + rg] = ap1[rg];
        }
    }
    __syncthreads();  // S4: partials ready
    float llm[2];
#pragma unroll
    for (int rh = 0; rh < 2; ++rh) {
        const int slot = rh * 32 + pr;
        const int bsub = slot >> 4, toff = slot & 15;
        const int mm = slot & 15;
        const int lane_c = ((mm >> 2) * 16 + (pc & 15));
        const int rgc = mm & 3, ntv = pc >> 4;
        float pv = b2v;
#pragma unroll
        for (int kg = 0; kg < 4; ++kg)
            pv += ppf[((kg * 4 + bsub) * 2 + ntv) * 256 + lane_c * 4 + rgc];
        const int half = lane & 32;
        float meanv = __shfl(pv, half + ((pc + 10) & 31), 64);
        float lsigv = __shfl(pv, half + ((pc + 20) & 31), 64);
        float e1, e2;
        if (pc < 10) {
            float ztar = z[(size_t)(b0 + bsub) * DD + t0 + tg * 16 + toff];
            float invs = __expf(-lsigv);
            float dd = (ztar - meanv) * invs;
            e1 = -0.5f * dd * dd - lsigv - 0.91893853320467274f + pv;
            e2 = pv;
        } else { e1 = -FLT_MAX; e2 = -FLT_MAX; }
        float m1 = e1, m2 = e2;
#pragma unroll
        for (int off = 16; off > 0; off >>= 1) {
            m1 = fmaxf(m1, __shfl_xor(m1, off, 64));
            m2 = fmaxf(m2, __shfl_xor(m2, off, 64));
        }
        float s1 = (pc < 10) ? __expf(e1 - m1) : 0.0f;
        float s2 = (pc < 10) ? __expf(e2 - m2) : 0.0f;
#pragma unroll
        for (int off = 16; off > 0; off >>= 1) {
            s1 += __shfl_xor(s1, off, 64);
            s2 += __shfl_xor(s2, off, 64);
        }
        float ll = (m1 + __logf(s1)) - (m2 + __logf(s2));
        llm[rh] = ll * maskbuf[(size_t)(b0 + bsub) * DD + t0 + tg * 16 + toff];
    }
    __syncthreads();  // S5
    if (pc == 0) { ppf[pr] = llm[0]; ppf[32 + pr] = llm[1]; }
    __syncthreads();  // S6
    if (tid < 4) {
        float s = 0.0f;
#pragma unroll
        for (int j = 0; j < 16; ++j) s += ppf[tid * 16 + j];
        atomicAdd(&out[b0 + tid], s);
    }
}

extern "C" void kernel_launch(void* const* d_in, const int* in_sizes, int n_in,
                              void* d_out, int out_size, void* d_ws, size_t ws_size,
                              hipStream_t stream) {
    const float* z   = (const float*)d_in[0];
    const float* c   = (const float*)d_in[1];
    const float* b   = (const float*)d_in[2];
    const float* m   = (const float*)d_in[3];
    const float* Wih = (const float*)d_in[4];
    const float* Whh = (const float*)d_in[5];
    const float* bih = (const float*)d_in[6];
    const float* bhh = (const float*)d_in[7];
    const float* W0  = (const float*)d_in[8];
    const float* b0  = (const float*)d_in[9];
    const float* W1  = (const float*)d_in[10];
    const float* b1  = (const float*)d_in[11];
    const float* W2  = (const float*)d_in[12];
    const float* b2  = (const float*)d_in[13];
    float* out = (float*)d_out;

    char* p = (char*)d_ws;
    unsigned short* constbf = (unsigned short*)p;  p += (size_t)BN * CWP * 2;
    float* gi_const  = (float*)p;                  p += (size_t)BN * G3 * 4;
    float* mlp_const = (float*)p;                  p += (size_t)BN * HIDD * 4;
    float* maskbuf   = (float*)p;                  p += (size_t)BN * DD * 4;
    unsigned short* WihP = (unsigned short*)p;     p += (size_t)96 * 17 * 512 * 2;
    unsigned short* W0cP = (unsigned short*)p;     p += (size_t)32 * 17 * 512 * 2;
    unsigned short* W0hP = (unsigned short*)p;     p += (size_t)32 * 16 * 512 * 2;
    unsigned short* W1P  = (unsigned short*)p;     p += (size_t)32 * 16 * 512 * 2;
    unsigned short* W2P  = (unsigned short*)p;     p += (size_t)2 * 16 * 512 * 2;
    unsigned char* Whh8P = (unsigned char*)p;      p += (size_t)96 * 8 * 64 * 16;  // paired fp8, all 3 gates
    float* hstate        = (float*)p;              p += (size_t)BN * HH * 4;
    unsigned short* h2g  = (unsigned short*)p;

    const size_t base = (size_t)(p - (char*)d_ws);
    const size_t slab_per_t = (size_t)BN * 512 * 2;
    int TC = 0;
    if (ws_size > base) {
        TC = (int)((ws_size - base) / slab_per_t);
        TC = (TC / 16) * 16;
        if (TC > DD) TC = DD;
    }
    if (TC < 16) return;  // workspace contract: harness ws ample (verified R8-R12)

    build_constbf<<<(BN * CWP + 255) / 256, 256, 0, stream>>>(c, b, m, constbf);
    pack_wN<<<96 * 17, 64, 0, stream>>>(Wih + G3, WihP, 17, G3, G3, CW);
    pack_wN<<<32 * 17, 64, 0, stream>>>(W0 + (size_t)HH * HIDD, W0cP, 17, HIDD, HIDD, CW);
    pack_w8p<<<96 * 8, 64, 0, stream>>>(Whh, Whh8P, G3);   // all 1536 cols, paired kc
    pack_wN<<<32 * 16, 64, 0, stream>>>(W0,  W0hP, 16, HIDD, HIDD, HH);
    pack_wN<<<32 * 16, 64, 0, stream>>>(W1,  W1P,  16, HIDD, HIDD, HH);
    pack_wN<<<2 * 16, 64, 0, stream>>>(W2,  W2P,  16, 30, 30, HH);
    gemm_const_mfma<6><<<BN / 16, 1024, 0, stream>>>(constbf, WihP, bih, gi_const, G3);
    gemm_const_mfma<2><<<BN / 16, 1024, 0, stream>>>(constbf, W0cP, b0, mlp_const, HIDD);
    sort_mask<<<BN, 128, 0, stream>>>(b, m, maskbuf);

    zero_f32<<<(BN * HH + 255) / 256, 256, 0, stream>>>(hstate, BN * HH);
    zero_f32<<<(BN + 255) / 256, 256, 0, stream>>>(out, BN);
    for (int t0 = 0; t0 < DD; t0 += TC) {
        int tlen = DD - t0 < TC ? DD - t0 : TC;
        gru_rec_chunk<<<BN / 16, 1024, 0, stream>>>(z, Wih, bhh, gi_const, Whh8P,
                                                    hstate, h2g, t0, tlen);
        dim3 gh(BN / 4, tlen / 16);
        head_mdn64<<<gh, 1024, 0, stream>>>(z, b1, b2, mlp_const, maskbuf, h2g,
                                            W0hP, W1P, W2P, out, t0);
    }
}

// Round 14
// 2604.747 us; speedup vs baseline: 1.4747x; 1.4747x over previous
//
#include <hip/hip_runtime.h>
#include <hip/hip_bf16.h>
#include <float.h>
#include <math.h>

#define BN   4096
#define DD   112
#define HH   512
#define G3   1536
#define CW   536
#define CWP  544     // K padded to 17*32
#define HIDD 512

typedef __attribute__((ext_vector_type(8))) short short8;
typedef __attribute__((ext_vector_type(4))) float float4v;

__device__ __forceinline__ unsigned short f2bf(float x) {
    __hip_bfloat16 h = __float2bfloat16(x);
    return *(unsigned short*)&h;
}

// ---------------- const = [c | b | m | 0pad]  (B x 544) bf16 ----------------
__global__ void build_constbf(const float* __restrict__ c, const float* __restrict__ b,
                              const float* __restrict__ m, unsigned short* __restrict__ out) {
    int idx = blockIdx.x * blockDim.x + threadIdx.x;
    if (idx >= BN * CWP) return;
    int row = idx / CWP, col = idx - row * CWP;
    float v;
    if (col < 312)      v = c[row * 312 + col];
    else if (col < 424) v = b[row * 112 + (col - 312)];
    else if (col < 536) v = m[row * 112 + (col - 424)];
    else                v = 0.0f;
    out[idx] = f2bf(v);
}

__global__ void zero_f32(float* __restrict__ p, int n) {
    int i = blockIdx.x * blockDim.x + threadIdx.x;
    if (i < n) p[i] = 0.0f;
}

// ---------------- pack weight [K][N] -> MFMA B-fragments (zero-padded) ----------------
__global__ void pack_wN(const float* __restrict__ src, unsigned short* __restrict__ dst,
                        int kchunks, int ldn, int ncols, int nrows) {
    int bid = blockIdx.x;
    int nt = bid / kchunks, kc = bid - nt * kchunks;
    int lane = threadIdx.x;
    int quad = lane >> 4, l16 = lane & 15;
    int n = nt * 16 + l16;
    unsigned short v[8];
#pragma unroll
    for (int j = 0; j < 8; ++j) {
        int k = kc * 32 + quad * 8 + j;
        float f = (k < nrows && n < ncols) ? src[(size_t)k * ldn + n] : 0.0f;
        v[j] = f2bf(f);
    }
    unsigned short* p = dst + ((size_t)bid * 64 + lane) * 8;
#pragma unroll
    for (int j = 0; j < 8; ++j) p[j] = v[j];
}

// ---------------- bf16 MFMA GEMM: C[B x N] = A[B x 544] @ Wp + bias ----------------
template<int TPW>
__global__ __launch_bounds__(1024) void gemm_const_mfma(
    const unsigned short* __restrict__ A, const unsigned short* __restrict__ BP,
    const float* __restrict__ bias, float* __restrict__ C, int N)
{
    const int tid = threadIdx.x;
    const int wave = tid >> 6, lane = tid & 63;
    const int quad = lane >> 4, l16 = lane & 15;
    const int rowBase = blockIdx.x * 16;
    const short8* BF = (const short8*)BP;
    float4v acc[TPW];
#pragma unroll
    for (int i = 0; i < TPW; ++i) {
        float bv = bias[(wave + 16 * i) * 16 + l16];
        acc[i] = (float4v){bv, bv, bv, bv};
    }
#pragma unroll 4
    for (int kc = 0; kc < 17; ++kc) {
        short8 af = *(const short8*)&A[(size_t)(rowBase + l16) * CWP + kc * 32 + quad * 8];
#pragma unroll
        for (int i = 0; i < TPW; ++i) {
            int tile = wave + 16 * i;
            acc[i] = __builtin_amdgcn_mfma_f32_16x16x32_bf16(af, BF[(tile * 17 + kc) * 64 + lane], acc[i], 0, 0, 0);
        }
    }
#pragma unroll
    for (int i = 0; i < TPW; ++i) {
        int col = (wave + 16 * i) * 16 + l16;
#pragma unroll
        for (int rg = 0; rg < 4; ++rg)
            C[(size_t)(rowBase + quad * 4 + rg) * N + col] = acc[i][rg];
    }
}

// ---------------- mask = descending sort of m*(1-b) per row ----------------
__global__ void sort_mask(const float* __restrict__ b, const float* __restrict__ m,
                          float* __restrict__ maskbuf) {
    __shared__ float s[128];
    const int row = blockIdx.x, t = threadIdx.x;
    float v = -FLT_MAX;
    if (t < DD) v = m[row * DD + t] * (1.0f - b[row * DD + t]);
    s[t] = v;
    __syncthreads();
    for (int k = 2; k <= 128; k <<= 1) {
        for (int j = k >> 1; j > 0; j >>= 1) {
            int ixj = t ^ j;
            if (ixj > t) {
                bool up = ((t & k) == 0);
                float a = s[t], bb = s[ixj];
                if ((a > bb) == up) { s[t] = bb; s[ixj] = a; }
            }
            __syncthreads();
        }
    }
    if (t < DD) maskbuf[row * DD + t] = s[127 - t];
}

// ================= KERNEL A: GRU recurrence chunk, dbuf h, phase-staggered K-loop =================
__global__ __launch_bounds__(1024, 4) void gru_rec_chunk(
    const float* __restrict__ z, const float* __restrict__ Wih,
    const float* __restrict__ bhh, const float* __restrict__ gi_const,
    const unsigned short* __restrict__ WhhP,
    float* __restrict__ hstate, unsigned short* __restrict__ h2g,
    int t0, int tlen)
{
    __shared__ unsigned short h_bf[2][16 * 520];
    __shared__ float zbuf[113 * 16];

    const int tid = threadIdx.x;
    const int wave = tid >> 6, lane = tid & 63;
    const int quad = lane >> 4, l16 = lane & 15;
    const int rowBase = blockIdx.x * 16;
    const int phase = blockIdx.x & 15;   // de-phase L2 weight sweep across blocks

    for (int idx = tid; idx < 113 * 16; idx += 1024) {
        int tt = idx >> 4, r = idx & 15;
        zbuf[idx] = (tt == 0) ? -1.0f : z[(rowBase + r) * DD + tt - 1];
    }

    int hcol[2];
    float wz0[2], wz1[2], wz2[2], bh2r[2];
    float gic0[2][4], gic1[2][4], gic2[2][4];
    float h_own[2][4];
#pragma unroll
    for (int i = 0; i < 2; ++i) {
        int tile = wave + 16 * i;
        int hc = tile * 16 + l16;
        hcol[i] = hc;
        wz0[i] = Wih[hc]; wz1[i] = Wih[512 + hc]; wz2[i] = Wih[1024 + hc];
        float bh0 = bhh[hc], bh1 = bhh[512 + hc];
        bh2r[i] = bhh[1024 + hc];
#pragma unroll
        for (int rg = 0; rg < 4; ++rg) {
            int m = quad * 4 + rg;
            const float* g = gi_const + (size_t)(rowBase + m) * G3;
            gic0[i][rg] = g[hc] + bh0;
            gic1[i][rg] = g[512 + hc] + bh1;
            gic2[i][rg] = g[1024 + hc];
            float hv = hstate[(size_t)(rowBase + m) * HH + hc];
            h_own[i][rg] = hv;
            h_bf[0][m * 520 + hc] = f2bf(hv);
        }
    }
    const short8* WhhF = (const short8*)WhhP;
    __syncthreads();

    for (int tt = 0; tt < tlen; ++tt) {
        const int t = t0 + tt;
        const int p = tt & 1;
        const unsigned short* hsrc = h_bf[p];
        unsigned short* hdst = h_bf[p ^ 1];
        float4v accR[2], accU[2], accN[2];
#pragma unroll
        for (int i = 0; i < 2; ++i) {
            accR[i] = (float4v){gic0[i][0], gic0[i][1], gic0[i][2], gic0[i][3]};
            accU[i] = (float4v){gic1[i][0], gic1[i][1], gic1[i][2], gic1[i][3]};
            accN[i] = (float4v){0.f, 0.f, 0.f, 0.f};
        }
#pragma unroll 8
        for (int kk = 0; kk < 16; ++kk) {
            const int kc = (kk + phase) & 15;
            short8 af = *(const short8*)&hsrc[l16 * 520 + kc * 32 + quad * 8];
#pragma unroll
            for (int i = 0; i < 2; ++i) {
                int tile = wave + 16 * i;
                accR[i] = __builtin_amdgcn_mfma_f32_16x16x32_bf16(af, WhhF[(tile * 16 + kc) * 64 + lane], accR[i], 0, 0, 0);
                accU[i] = __builtin_amdgcn_mfma_f32_16x16x32_bf16(af, WhhF[((tile + 32) * 16 + kc) * 64 + lane], accU[i], 0, 0, 0);
                accN[i] = __builtin_amdgcn_mfma_f32_16x16x32_bf16(af, WhhF[((tile + 64) * 16 + kc) * 64 + lane], accN[i], 0, 0, 0);
            }
        }
#pragma unroll
        for (int i = 0; i < 2; ++i) {
#pragma unroll
            for (int rg = 0; rg < 4; ++rg) {
                int m = quad * 4 + rg;
                float zt = zbuf[t * 16 + m];
                float r = 1.0f / (1.0f + __expf(-(accR[i][rg] + zt * wz0[i])));
                float u = 1.0f / (1.0f + __expf(-(accU[i][rg] + zt * wz1[i])));
                float xn = gic2[i][rg] + zt * wz2[i] + r * (accN[i][rg] + bh2r[i]);
                float n = 1.0f - 2.0f / (__expf(2.0f * xn) + 1.0f);
                float h2 = (1.0f - u) * n + u * h_own[i][rg];
                h_own[i][rg] = h2;
                hdst[m * 520 + hcol[i]] = f2bf(h2);
            }
        }
        __syncthreads();  // single barrier: hdst complete
        {
            int col = lane * 8;
            uint4 v = *(const uint4*)&hdst[wave * 520 + col];
            *(uint4*)&h2g[((size_t)tt * BN + rowBase + wave) * 512 + col] = v;
        }
    }
#pragma unroll
    for (int i = 0; i < 2; ++i)
#pragma unroll
        for (int rg = 0; rg < 4; ++rg)
            hstate[(size_t)(rowBase + quad * 4 + rg) * HH + hcol[i]] = h_own[i][rg];
}

// ================= KERNEL B: MLP head + MDN, M=64, phase-staggered K-loops =================
__global__ __launch_bounds__(1024) void head_mdn64(
    const float* __restrict__ z, const float* __restrict__ b1,
    const float* __restrict__ b2, const float* __restrict__ mlp_const,
    const float* __restrict__ maskbuf, const unsigned short* __restrict__ h2g,
    const unsigned short* __restrict__ W0hP, const unsigned short* __restrict__ W1P,
    const unsigned short* __restrict__ W2P, float* __restrict__ out, int t0)
{
    __shared__ unsigned short h_bf[64 * 520];   // h2, later a2
    __shared__ unsigned short a_bf[64 * 520];   // a1, later pp (float alias)
    float* ppf = (float*)a_bf;

    const int tid = threadIdx.x;
    const int wave = tid >> 6, lane = tid & 63;
    const int quad = lane >> 4, l16 = lane & 15;
    const int pr = tid >> 5, pc = tid & 31;
    const int b0 = blockIdx.x * 4;
    const int tg = blockIdx.y;
    const int phase = blockIdx.x & 15;

    {
        int flat = tid * 32;
        int r = flat >> 9, col = flat & 511;
        int bb = b0 + (r >> 4), trel = tg * 16 + (r & 15);
        const uint4* src = (const uint4*)&h2g[((size_t)trel * BN + bb) * 512 + col];
        uint4 v0 = src[0], v1 = src[1], v2 = src[2], v3 = src[3];
        uint4* dst = (uint4*)&h_bf[r * 520 + col];
        dst[0] = v0; dst[1] = v1; dst[2] = v2; dst[3] = v3;
    }
    int hcol[2];
    float b1c[2], mlc[2][4];
#pragma unroll
    for (int i = 0; i < 2; ++i) {
        int hc = (wave + 16 * i) * 16 + l16;
        hcol[i] = hc;
        b1c[i] = b1[hc];
#pragma unroll
        for (int mt = 0; mt < 4; ++mt) mlc[i][mt] = mlp_const[(size_t)(b0 + mt) * HIDD + hc];
    }
    const float b2v = (pc < 30) ? b2[pc] : 0.0f;
    const short8* W0hF = (const short8*)W0hP;
    const short8* W1F  = (const short8*)W1P;
    const short8* W2F  = (const short8*)W2P;
    __syncthreads();  // S0: h staged

    // ---- a1 = tanh(h2 @ W0h + mlc[b]) ----
    float4v acc1[2][4];
#pragma unroll
    for (int i = 0; i < 2; ++i)
#pragma unroll
        for (int mt = 0; mt < 4; ++mt)
            acc1[i][mt] = (float4v){mlc[i][mt], mlc[i][mt], mlc[i][mt], mlc[i][mt]};
#pragma unroll 2
    for (int kk = 0; kk < 16; ++kk) {
        const int kc = (kk + phase) & 15;
        short8 af[4];
#pragma unroll
        for (int mt = 0; mt < 4; ++mt)
            af[mt] = *(const short8*)&h_bf[(mt * 16 + l16) * 520 + kc * 32 + quad * 8];
#pragma unroll
        for (int i = 0; i < 2; ++i) {
            short8 bf = W0hF[((wave + 16 * i) * 16 + kc) * 64 + lane];
#pragma unroll
            for (int mt = 0; mt < 4; ++mt)
                acc1[i][mt] = __builtin_amdgcn_mfma_f32_16x16x32_bf16(af[mt], bf, acc1[i][mt], 0, 0, 0);
        }
    }
#pragma unroll
    for (int i = 0; i < 2; ++i)
#pragma unroll
        for (int mt = 0; mt < 4; ++mt)
#pragma unroll
            for (int rg = 0; rg < 4; ++rg) {
                int m = mt * 16 + quad * 4 + rg;
                float x = acc1[i][mt][rg];
                a_bf[m * 520 + hcol[i]] = f2bf(1.0f - 2.0f / (__expf(2.0f * x) + 1.0f));
            }
    __syncthreads();  // S1: a1 ready
    // ---- a2 = tanh(a1 @ W1 + b1) ----
    float4v acc2[2][4];
#pragma unroll
    for (int i = 0; i < 2; ++i)
#pragma unroll
        for (int mt = 0; mt < 4; ++mt)
            acc2[i][mt] = (float4v){b1c[i], b1c[i], b1c[i], b1c[i]};
#pragma unroll 2
    for (int kk = 0; kk < 16; ++kk) {
        const int kc = (kk + phase) & 15;
        short8 af[4];
#pragma unroll
        for (int mt = 0; mt < 4; ++mt)
            af[mt] = *(const short8*)&a_bf[(mt * 16 + l16) * 520 + kc * 32 + quad * 8];
#pragma unroll
        for (int i = 0; i < 2; ++i) {
            short8 bf = W1F[((wave + 16 * i) * 16 + kc) * 64 + lane];
#pragma unroll
            for (int mt = 0; mt < 4; ++mt)
                acc2[i][mt] = __builtin_amdgcn_mfma_f32_16x16x32_bf16(af[mt], bf, acc2[i][mt], 0, 0, 0);
        }
    }
    __syncthreads();  // S2: a1 reads done
#pragma unroll
    for (int i = 0; i < 2; ++i)
#pragma unroll
        for (int mt = 0; mt < 4; ++mt)
#pragma unroll
            for (int rg = 0; rg < 4; ++rg) {
                int m = mt * 16 + quad * 4 + rg;
                float x = acc2[i][mt][rg];
                h_bf[m * 520 + hcol[i]] = f2bf(1.0f - 2.0f / (__expf(2.0f * x) + 1.0f));
            }
    __syncthreads();  // S3: a2 ready
    // ---- p = a2 @ W2 + b2 ----
    {
        const int mtw = wave >> 2, kg = wave & 3;
        float4v ap0 = (float4v){0.f, 0.f, 0.f, 0.f}, ap1 = (float4v){0.f, 0.f, 0.f, 0.f};
#pragma unroll
        for (int kk = 0; kk < 4; ++kk) {
            int kc = kg * 4 + kk;
            short8 af = *(const short8*)&h_bf[(mtw * 16 + l16) * 520 + kc * 32 + quad * 8];
            ap0 = __builtin_amdgcn_mfma_f32_16x16x32_bf16(af, W2F[(0 * 16 + kc) * 64 + lane], ap0, 0, 0, 0);
            ap1 = __builtin_amdgcn_mfma_f32_16x16x32_bf16(af, W2F[(1 * 16 + kc) * 64 + lane], ap1, 0, 0, 0);
        }
#pragma unroll
        for (int rg = 0; rg < 4; ++rg) {
            ppf[((kg * 4 + mtw) * 2 + 0) * 256 + lane * 4 + rg] = ap0[rg];
            ppf[((kg * 4 + mtw) * 2 + 1) * 256 + lane * 4 + rg] = ap1[rg];
        }
    }
    __syncthreads();  // S4: partials ready
    float llm[2];
#pragma unroll
    for (int rh = 0; rh < 2; ++rh) {
        const int slot = rh * 32 + pr;
        const int bsub = slot >> 4, toff = slot & 15;
        const int mm = slot & 15;
        const int lane_c = ((mm >> 2) * 16 + (pc & 15));
        const int rgc = mm & 3, ntv = pc >> 4;
        float pv = b2v;
#pragma unroll
        for (int kg = 0; kg < 4; ++kg)
            pv += ppf[((kg * 4 + bsub) * 2 + ntv) * 256 + lane_c * 4 + rgc];
        const int half = lane & 32;
        float meanv = __shfl(pv, half + ((pc + 10) & 31), 64);
        float lsigv = __shfl(pv, half + ((pc + 20) & 31), 64);
        float e1, e2;
        if (pc < 10) {
            float ztar = z[(size_t)(b0 + bsub) * DD + t0 + tg * 16 + toff];
            float invs = __expf(-lsigv);
            float dd = (ztar - meanv) * invs;
            e1 = -0.5f * dd * dd - lsigv - 0.91893853320467274f + pv;
            e2 = pv;
        } else { e1 = -FLT_MAX; e2 = -FLT_MAX; }
        float m1 = e1, m2 = e2;
#pragma unroll
        for (int off = 16; off > 0; off >>= 1) {
            m1 = fmaxf(m1, __shfl_xor(m1, off, 64));
            m2 = fmaxf(m2, __shfl_xor(m2, off, 64));
        }
        float s1 = (pc < 10) ? __expf(e1 - m1) : 0.0f;
        float s2 = (pc < 10) ? __expf(e2 - m2) : 0.0f;
#pragma unroll
        for (int off = 16; off > 0; off >>= 1) {
            s1 += __shfl_xor(s1, off, 64);
            s2 += __shfl_xor(s2, off, 64);
        }
        float ll = (m1 + __logf(s1)) - (m2 + __logf(s2));
        llm[rh] = ll * maskbuf[(size_t)(b0 + bsub) * DD + t0 + tg * 16 + toff];
    }
    __syncthreads();  // S5
    if (pc == 0) { ppf[pr] = llm[0]; ppf[32 + pr] = llm[1]; }
    __syncthreads();  // S6
    if (tid < 4) {
        float s = 0.0f;
#pragma unroll
        for (int j = 0; j < 16; ++j) s += ppf[tid * 16 + j];
        atomicAdd(&out[b0 + tid], s);
    }
}

extern "C" void kernel_launch(void* const* d_in, const int* in_sizes, int n_in,
                              void* d_out, int out_size, void* d_ws, size_t ws_size,
                              hipStream_t stream) {
    const float* z   = (const float*)d_in[0];
    const float* c   = (const float*)d_in[1];
    const float* b   = (const float*)d_in[2];
    const float* m   = (const float*)d_in[3];
    const float* Wih = (const float*)d_in[4];
    const float* Whh = (const float*)d_in[5];
    const float* bih = (const float*)d_in[6];
    const float* bhh = (const float*)d_in[7];
    const float* W0  = (const float*)d_in[8];
    const float* b0  = (const float*)d_in[9];
    const float* W1  = (const float*)d_in[10];
    const float* b1  = (const float*)d_in[11];
    const float* W2  = (const float*)d_in[12];
    const float* b2  = (const float*)d_in[13];
    float* out = (float*)d_out;

    char* p = (char*)d_ws;
    unsigned short* constbf = (unsigned short*)p;  p += (size_t)BN * CWP * 2;
    float* gi_const  = (float*)p;                  p += (size_t)BN * G3 * 4;
    float* mlp_const = (float*)p;                  p += (size_t)BN * HIDD * 4;
    float* maskbuf   = (float*)p;                  p += (size_t)BN * DD * 4;
    unsigned short* WihP = (unsigned short*)p;     p += (size_t)96 * 17 * 512 * 2;
    unsigned short* W0cP = (unsigned short*)p;     p += (size_t)32 * 17 * 512 * 2;
    unsigned short* WhhP = (unsigned short*)p;     p += (size_t)96 * 16 * 512 * 2;
    unsigned short* W0hP = (unsigned short*)p;     p += (size_t)32 * 16 * 512 * 2;
    unsigned short* W1P  = (unsigned short*)p;     p += (size_t)32 * 16 * 512 * 2;
    unsigned short* W2P  = (unsigned short*)p;     p += (size_t)2 * 16 * 512 * 2;
    float* hstate        = (float*)p;              p += (size_t)BN * HH * 4;
    unsigned short* h2g  = (unsigned short*)p;

    const size_t base = (size_t)(p - (char*)d_ws);
    const size_t slab_per_t = (size_t)BN * 512 * 2;
    int TC = 0;
    if (ws_size > base) {
        TC = (int)((ws_size - base) / slab_per_t);
        TC = (TC / 16) * 16;
        if (TC > DD) TC = DD;
    }
    if (TC < 16) return;  // workspace contract: harness ws ample (verified R8-R13)

    build_constbf<<<(BN * CWP + 255) / 256, 256, 0, stream>>>(c, b, m, constbf);
    pack_wN<<<96 * 17, 64, 0, stream>>>(Wih + G3, WihP, 17, G3, G3, CW);
    pack_wN<<<32 * 17, 64, 0, stream>>>(W0 + (size_t)HH * HIDD, W0cP, 17, HIDD, HIDD, CW);
    pack_wN<<<96 * 16, 64, 0, stream>>>(Whh, WhhP, 16, G3, G3, HH);
    pack_wN<<<32 * 16, 64, 0, stream>>>(W0,  W0hP, 16, HIDD, HIDD, HH);
    pack_wN<<<32 * 16, 64, 0, stream>>>(W1,  W1P,  16, HIDD, HIDD, HH);
    pack_wN<<<2 * 16, 64, 0, stream>>>(W2,  W2P,  16, 30, 30, HH);
    gemm_const_mfma<6><<<BN / 16, 1024, 0, stream>>>(constbf, WihP, bih, gi_const, G3);
    gemm_const_mfma<2><<<BN / 16, 1024, 0, stream>>>(constbf, W0cP, b0, mlp_const, HIDD);
    sort_mask<<<BN, 128, 0, stream>>>(b, m, maskbuf);

    zero_f32<<<(BN * HH + 255) / 256, 256, 0, stream>>>(hstate, BN * HH);
    zero_f32<<<(BN + 255) / 256, 256, 0, stream>>>(out, BN);
    for (int t0 = 0; t0 < DD; t0 += TC) {
        int tlen = DD - t0 < TC ? DD - t0 : TC;
        gru_rec_chunk<<<BN / 16, 1024, 0, stream>>>(z, Wih, bhh, gi_const, WhhP,
                                                    hstate, h2g, t0, tlen);
        dim3 gh(BN / 4, tlen / 16);
        head_mdn64<<<gh, 1024, 0, stream>>>(z, b1, b2, mlp_const, maskbuf, h2g,
                                            W0hP, W1P, W2P, out, t0);
    }
}